// Round 17
// baseline (1348.260 us; speedup 1.0000x reference)
//
#include <hip/hip_runtime.h>

#define TT 512
#define HH 256

typedef _Float16 half2t __attribute__((ext_vector_type(2)));

// fp16-pair dot with fp32 accumulate (v_dot2_f32_f16 when available).
__device__ __forceinline__ float dot2acc(unsigned w, unsigned h, float acc) {
#if __has_builtin(__builtin_amdgcn_fdot2)
    return __builtin_amdgcn_fdot2(__builtin_bit_cast(half2t, w),
                                  __builtin_bit_cast(half2t, h), acc, false);
#else
    union U { unsigned u; _Float16 f[2]; };
    U uw, uh; uw.u = w; uh.u = h;
    acc = __builtin_fmaf((float)uw.f[0], (float)uh.f[0], acc);
    acc = __builtin_fmaf((float)uw.f[1], (float)uh.f[1], acc);
    return acc;
#endif
}

__device__ __forceinline__ unsigned packh2(float a, float b) {
    union U { _Float16 f[2]; unsigned u; } r;
    r.f[0] = (_Float16)a; r.f[1] = (_Float16)b;   // RNE conversion
    return r.u;
}

// Force a packed word into an AGPR (unified file, MFMA-free kernel).
#define AGPR_W(dst, src) \
    asm volatile("v_accvgpr_write_b32 %0, %1" : "=a"(dst) : "v"(src))
#define AGPR_R(dst, src) \
    asm("v_accvgpr_read_b32 %0, %1" : "=v"(dst) : "a"(src))

// C=1: one 512-thread wg per batch (128 wgs, plain launch), no cross-CU
// exchange. Thread j owns gate-rows j (i/f) and j+512 (g/o), 256 packed
// fp16 words total. R15/R16 lesson: the allocator caps ARCH VGPRs at 128
// for 8-wave blocks -> 192 VGPR-resident words spilled to scratch
// (~1.5us/step L2 reload + 25-35ms scratch first-touch outlier).
// R17: weights live in AGPRs (explicit v_accvgpr_write/read, "a"
// constraints -- the allocator cannot refuse a constraint). Budget/wave:
// 184 AGPR + ~60 arch + 72 LDS words (144KB tail) <= 256 unified, 8 waves
// x 256 = full CU file. Zero scratch by construction.
__global__ __launch_bounds__(512)
__attribute__((amdgpu_waves_per_eu(2, 2)))
void lstm_single(
    const float* __restrict__ x,      // [B,T]
    const float* __restrict__ W_ih,   // [1024]
    const float* __restrict__ W_hh,   // [1024,256]
    const float* __restrict__ b_ih,   // [1024]
    const float* __restrict__ b_hh,   // [1024]
    const float* __restrict__ W1,     // [128,256]
    const float* __restrict__ b1,     // [128]
    const float* __restrict__ W2,     // [128]
    const float* __restrict__ b2,     // [1]
    float* __restrict__ out)          // [B]
{
    const int b = blockIdx.x;
    const int j = threadIdx.x;        // 0..511

    __shared__ unsigned wl[18][512][4];   // 144 KB: LDS weight tail (words 92..127/row)
    __shared__ unsigned h_lds[128];       // 512 B: h as fp16 pairs
    __shared__ float    h32[HH];          // 1 KB: h fp32 (epilogue)
    __shared__ float    gates[1024];      // 4 KB
    __shared__ float    x_lds[TT];        // 2 KB
    __shared__ float    red[128];         // 512 B
    // total LDS = 152 KB -> 1 wg/CU

    const int rA = j;                 // gate-rows: rA in {i,f}, rB in {g,o}
    const int rB = j + 512;
    const float* pA = W_hh + (size_t)rA * HH;
    const float* pB = W_hh + (size_t)rB * HH;

    // ---- stage weights: words 0..91 of each row -> 184 AGPRs
    unsigned wagA[92], wagB[92];
    #pragma unroll
    for (int k = 0; k < 92; ++k) {
        unsigned p = packh2(pA[2 * k], pA[2 * k + 1]);
        AGPR_W(wagA[k], p);
    }
    #pragma unroll
    for (int k = 0; k < 92; ++k) {
        unsigned p = packh2(pB[2 * k], pB[2 * k + 1]);
        AGPR_W(wagB[k], p);
    }
    // ---- words 92..127 of each row -> LDS (9 uint4 blocks per row)
    #pragma unroll
    for (int blk = 0; blk < 9; ++blk) {
        #pragma unroll
        for (int u = 0; u < 4; ++u) {
            const int k = 2 * (92 + blk * 4 + u);    // fp32 element index
            wl[blk][j][u]     = packh2(pA[k], pA[k + 1]);
            wl[9 + blk][j][u] = packh2(pB[k], pB[k + 1]);
        }
    }

    // per-row input weight + bias
    const float wihA  = W_ih[rA];
    const float biasA = b_ih[rA] + b_hh[rA];
    const float wihB  = W_ih[rB];
    const float biasB = b_ih[rB] + b_hh[rB];

    // stage x; init h
    x_lds[j] = x[(size_t)b * TT + j];
    if (j < 128) h_lds[j] = 0u;
    if (j < 256) h32[j] = 0.0f;
    float c = 0.0f;                   // cell state (threads 0..255, elem j)
    __syncthreads();

    for (int t = 0; t < TT; ++t) {
        // ---- dot: both rows vs full h (fp16 pairs), fp32 accumulate
        float accA = 0.f, accB = 0.f;
        const uint4* hq4 = reinterpret_cast<const uint4*>(h_lds);
        #pragma unroll
        for (int i = 0; i < 23; ++i) {                 // words 0..91 (AGPR weights)
            uint4 hq = hq4[i];                         // broadcast ds_read_b128
            unsigned a0, a1, a2, a3, b0, b1, b2, b3;
            AGPR_R(a0, wagA[4*i+0]); AGPR_R(b0, wagB[4*i+0]);
            AGPR_R(a1, wagA[4*i+1]); AGPR_R(b1, wagB[4*i+1]);
            AGPR_R(a2, wagA[4*i+2]); AGPR_R(b2, wagB[4*i+2]);
            AGPR_R(a3, wagA[4*i+3]); AGPR_R(b3, wagB[4*i+3]);
            accA = dot2acc(a0, hq.x, accA); accB = dot2acc(b0, hq.x, accB);
            accA = dot2acc(a1, hq.y, accA); accB = dot2acc(b1, hq.y, accB);
            accA = dot2acc(a2, hq.z, accA); accB = dot2acc(b2, hq.z, accB);
            accA = dot2acc(a3, hq.w, accA); accB = dot2acc(b3, hq.w, accB);
        }
        {   // AGPR words 88..91 are indices 4*22..4*22+3 -> covered above (i<23)
        }
        #pragma unroll
        for (int blk = 0; blk < 9; ++blk) {            // words 92..127 (LDS weights)
            uint4 hq  = hq4[23 + blk];
            uint4 wqA = *reinterpret_cast<const uint4*>(&wl[blk][j][0]);
            uint4 wqB = *reinterpret_cast<const uint4*>(&wl[9 + blk][j][0]);
            accA = dot2acc(wqA.x, hq.x, accA); accB = dot2acc(wqB.x, hq.x, accB);
            accA = dot2acc(wqA.y, hq.y, accA); accB = dot2acc(wqB.y, hq.y, accB);
            accA = dot2acc(wqA.z, hq.z, accA); accB = dot2acc(wqB.z, hq.z, accB);
            accA = dot2acc(wqA.w, hq.w, accA); accB = dot2acc(wqB.w, hq.w, accB);
        }
        const float xv = x_lds[t];
        gates[j]       = accA + __builtin_fmaf(xv, wihA, biasA);
        gates[j + 512] = accB + __builtin_fmaf(xv, wihB, biasB);
        __syncthreads();

        // ---- cell update: threads 0..255 (element j)
        if (j < 256) {
            float gi = gates[j];
            float gf = gates[256 + j];
            float gg = gates[512 + j];
            float go = gates[768 + j];
            gi = __builtin_amdgcn_rcpf(1.f + __expf(-gi));
            gf = __builtin_amdgcn_rcpf(1.f + __expf(-gf));
            go = __builtin_amdgcn_rcpf(1.f + __expf(-go));
            gg = 2.f * __builtin_amdgcn_rcpf(1.f + __expf(-2.f * gg)) - 1.f;
            c = __builtin_fmaf(gf, c, gi * gg);
            float th = 2.f * __builtin_amdgcn_rcpf(1.f + __expf(-2.f * c)) - 1.f;
            float hn = go * th;
            h32[j] = hn;
            reinterpret_cast<unsigned short*>(h_lds)[j] =
                __builtin_bit_cast(unsigned short, (_Float16)hn);
        }
        __syncthreads();
    }

    // ---- epilogue MLP: y = relu(h @ W1.T + b1) @ W2.T + b2
    if (j < 128) {
        const float4* w1p = reinterpret_cast<const float4*>(W1 + (size_t)j * HH);
        const float4* hp  = reinterpret_cast<const float4*>(h32);
        float s0 = 0.f, s1 = 0.f, s2 = 0.f, s3 = 0.f;
        #pragma unroll
        for (int k = 0; k < 64; ++k) {
            float4 wv = w1p[k], hv = hp[k];
            s0 = __builtin_fmaf(wv.x, hv.x, s0);
            s1 = __builtin_fmaf(wv.y, hv.y, s1);
            s2 = __builtin_fmaf(wv.z, hv.z, s2);
            s3 = __builtin_fmaf(wv.w, hv.w, s3);
        }
        float rv = fmaxf((s0 + s1) + (s2 + s3) + b1[j], 0.f);
        red[j] = rv * W2[j];
    }
    __syncthreads();
    if (j == 0) {
        float y = b2[0];
        #pragma unroll 4
        for (int k = 0; k < 128; ++k) y += red[k];
        out[b] = y;
    }
}

extern "C" void kernel_launch(void* const* d_in, const int* in_sizes, int n_in,
                              void* d_out, int out_size, void* d_ws, size_t ws_size,
                              hipStream_t stream) {
    const float* x    = (const float*)d_in[0];
    const float* W_ih = (const float*)d_in[1];
    const float* W_hh = (const float*)d_in[2];
    const float* b_ih = (const float*)d_in[3];
    const float* b_hh = (const float*)d_in[4];
    const float* W1   = (const float*)d_in[5];
    const float* b1   = (const float*)d_in[6];
    const float* W2   = (const float*)d_in[7];
    const float* b2   = (const float*)d_in[8];
    float* out = (float*)d_out;

    lstm_single<<<128, 512, 0, stream>>>(x, W_ih, W_hh, b_ih, b_hh,
                                         W1, b1, W2, b2, out);
}

// Round 18
// 1232.893 us; speedup vs baseline: 1.0936x; 1.0936x over previous
//
#include <hip/hip_runtime.h>

#define TT 512
#define HH 256

typedef _Float16 half2t __attribute__((ext_vector_type(2)));

// fp16-pair dot with fp32 accumulate (v_dot2_f32_f16 when available).
__device__ __forceinline__ float dot2acc(unsigned w, unsigned h, float acc) {
#if __has_builtin(__builtin_amdgcn_fdot2)
    return __builtin_amdgcn_fdot2(__builtin_bit_cast(half2t, w),
                                  __builtin_bit_cast(half2t, h), acc, false);
#else
    union U { unsigned u; _Float16 f[2]; };
    U uw, uh; uw.u = w; uh.u = h;
    acc = __builtin_fmaf((float)uw.f[0], (float)uh.f[0], acc);
    acc = __builtin_fmaf((float)uw.f[1], (float)uh.f[1], acc);
    return acc;
#endif
}

__device__ __forceinline__ unsigned packh2(float a, float b) {
    union U { _Float16 f[2]; unsigned u; } r;
    r.f[0] = (_Float16)a; r.f[1] = (_Float16)b;   // RNE conversion
    return r.u;
}

#define AGPR_W(dst, src) \
    asm volatile("v_accvgpr_write_b32 %0, %1" : "=a"(dst) : "v"(src))
#define AGPR_R(dst, src) \
    asm("v_accvgpr_read_b32 %0, %1" : "=v"(dst) : "a"(src))

// C=1, 1024 threads/wg, one wg per batch (128 wgs, plain launch).
// Thread j owns gate-row j (gate = j>>8): 128 packed fp16 words split
// 64 AGPR + 28 arch + 36 LDS. At 1024 thr = 16 waves = 4 waves/SIMD the
// per-wave budget is 128 regs total = 64 arch + 64 AGPR (exact HW quantum);
// R17's 2-waves/SIMD config couldn't hide LDS latency (VALUBusy 32%).
// h as 128 fp16-pair words in LDS (broadcast b128 reads). Each thread's
// acc = complete row sum -> no reduction, 2 barriers/step, no exchange,
// no atomics, no workspace, zero scratch (no spills by construction).
__global__ __launch_bounds__(1024)
__attribute__((amdgpu_waves_per_eu(4, 4)))
void lstm_single(
    const float* __restrict__ x,      // [B,T]
    const float* __restrict__ W_ih,   // [1024]
    const float* __restrict__ W_hh,   // [1024,256]
    const float* __restrict__ b_ih,   // [1024]
    const float* __restrict__ b_hh,   // [1024]
    const float* __restrict__ W1,     // [128,256]
    const float* __restrict__ b1,     // [128]
    const float* __restrict__ W2,     // [128]
    const float* __restrict__ b2,     // [1]
    float* __restrict__ out)          // [B]
{
    const int b = blockIdx.x;
    const int j = threadIdx.x;        // 0..1023 = gate-row

    __shared__ unsigned wl[9][1024][4];   // 144 KB: LDS weight tail (words 92..127)
    __shared__ unsigned h_lds[128];       // 512 B: h as fp16 pairs
    __shared__ float    h32[HH];          // 1 KB: h fp32 (epilogue)
    __shared__ float    gates[1024];      // 4 KB
    __shared__ float    x_lds[TT];        // 2 KB
    __shared__ float    red[128];         // 512 B
    // total ~152 KB -> 1 wg/CU

    const float* pR = W_hh + (size_t)j * HH;   // my row

    // ---- stage weights: words 0..63 -> 64 AGPRs
    unsigned wag[64];
    #pragma unroll
    for (int k = 0; k < 64; ++k) {
        unsigned p = packh2(pR[2 * k], pR[2 * k + 1]);
        AGPR_W(wag[k], p);
    }
    // ---- words 64..91 -> 28 arch VGPRs (opaque: no remat-from-global)
    unsigned wv[28];
    #pragma unroll
    for (int k = 0; k < 28; ++k)
        wv[k] = packh2(pR[2 * (64 + k)], pR[2 * (64 + k) + 1]);
    #pragma unroll
    for (int k = 0; k < 28; ++k)
        asm volatile("" : "+v"(wv[k]));
    // ---- words 92..127 -> LDS (9 uint4 blocks)
    #pragma unroll
    for (int blk = 0; blk < 9; ++blk) {
        #pragma unroll
        for (int u = 0; u < 4; ++u) {
            const int k = 2 * (92 + blk * 4 + u);
            wl[blk][j][u] = packh2(pR[k], pR[k + 1]);
        }
    }

    // per-row input weight + bias
    const float wih_r  = W_ih[j];
    const float bias_r = b_ih[j] + b_hh[j];

    // stage x; init h
    if (j < TT) x_lds[j] = x[(size_t)b * TT + j];
    if (j < 128) h_lds[j] = 0u;
    if (j < 256) h32[j] = 0.0f;
    float c = 0.0f;                   // cell state (threads 0..255, elem j)
    __syncthreads();

    for (int t = 0; t < TT; ++t) {
        float acc = 0.f;
        const uint4* hq4 = reinterpret_cast<const uint4*>(h_lds);
        // ---- words 0..63: AGPR weights (16 uint4 h blocks)
        #pragma unroll
        for (int i = 0; i < 16; ++i) {
            uint4 hq = hq4[i];                        // broadcast ds_read_b128
            unsigned w0, w1, w2, w3;
            AGPR_R(w0, wag[4*i+0]);
            AGPR_R(w1, wag[4*i+1]);
            AGPR_R(w2, wag[4*i+2]);
            AGPR_R(w3, wag[4*i+3]);
            acc = dot2acc(w0, hq.x, acc);
            acc = dot2acc(w1, hq.y, acc);
            acc = dot2acc(w2, hq.z, acc);
            acc = dot2acc(w3, hq.w, acc);
        }
        // ---- words 64..91: arch weights (7 uint4 h blocks)
        #pragma unroll
        for (int i = 0; i < 7; ++i) {
            uint4 hq = hq4[16 + i];
            acc = dot2acc(wv[4*i+0], hq.x, acc);
            acc = dot2acc(wv[4*i+1], hq.y, acc);
            acc = dot2acc(wv[4*i+2], hq.z, acc);
            acc = dot2acc(wv[4*i+3], hq.w, acc);
        }
        // ---- words 92..127: LDS weights (9 uint4 blocks)
        #pragma unroll
        for (int blk = 0; blk < 9; ++blk) {
            uint4 hq = hq4[23 + blk];
            uint4 wq = *reinterpret_cast<const uint4*>(&wl[blk][j][0]);
            acc = dot2acc(wq.x, hq.x, acc);
            acc = dot2acc(wq.y, hq.y, acc);
            acc = dot2acc(wq.z, hq.z, acc);
            acc = dot2acc(wq.w, hq.w, acc);
        }
        gates[j] = acc + __builtin_fmaf(x_lds[t], wih_r, bias_r);
        __syncthreads();

        // ---- cell update: threads 0..255 (element j)
        if (j < 256) {
            float gi = gates[j];
            float gf = gates[256 + j];
            float gg = gates[512 + j];
            float go = gates[768 + j];
            gi = __builtin_amdgcn_rcpf(1.f + __expf(-gi));
            gf = __builtin_amdgcn_rcpf(1.f + __expf(-gf));
            go = __builtin_amdgcn_rcpf(1.f + __expf(-go));
            gg = 2.f * __builtin_amdgcn_rcpf(1.f + __expf(-2.f * gg)) - 1.f;
            c = __builtin_fmaf(gf, c, gi * gg);
            float th = 2.f * __builtin_amdgcn_rcpf(1.f + __expf(-2.f * c)) - 1.f;
            float hn = go * th;
            h32[j] = hn;
            reinterpret_cast<unsigned short*>(h_lds)[j] =
                __builtin_bit_cast(unsigned short, (_Float16)hn);
        }
        __syncthreads();
    }

    // ---- epilogue MLP: y = relu(h @ W1.T + b1) @ W2.T + b2
    if (j < 128) {
        const float4* w1p = reinterpret_cast<const float4*>(W1 + (size_t)j * HH);
        const float4* hp  = reinterpret_cast<const float4*>(h32);
        float s0 = 0.f, s1 = 0.f, s2 = 0.f, s3 = 0.f;
        #pragma unroll
        for (int k = 0; k < 64; ++k) {
            float4 wv4 = w1p[k], hv = hp[k];
            s0 = __builtin_fmaf(wv4.x, hv.x, s0);
            s1 = __builtin_fmaf(wv4.y, hv.y, s1);
            s2 = __builtin_fmaf(wv4.z, hv.z, s2);
            s3 = __builtin_fmaf(wv4.w, hv.w, s3);
        }
        float rv = fmaxf((s0 + s1) + (s2 + s3) + b1[j], 0.f);
        red[j] = rv * W2[j];
    }
    __syncthreads();
    if (j == 0) {
        float y = b2[0];
        #pragma unroll 4
        for (int k = 0; k < 128; ++k) y += red[k];
        out[b] = y;
    }
}

extern "C" void kernel_launch(void* const* d_in, const int* in_sizes, int n_in,
                              void* d_out, int out_size, void* d_ws, size_t ws_size,
                              hipStream_t stream) {
    const float* x    = (const float*)d_in[0];
    const float* W_ih = (const float*)d_in[1];
    const float* W_hh = (const float*)d_in[2];
    const float* b_ih = (const float*)d_in[3];
    const float* b_hh = (const float*)d_in[4];
    const float* W1   = (const float*)d_in[5];
    const float* b1   = (const float*)d_in[6];
    const float* W2   = (const float*)d_in[7];
    const float* b2   = (const float*)d_in[8];
    float* out = (float*)d_out;

    lstm_single<<<128, 1024, 0, stream>>>(x, W_ih, W_hh, b_ih, b_hh,
                                          W1, b1, W2, b2, out);
}

// Round 19
// 1193.903 us; speedup vs baseline: 1.1293x; 1.0327x over previous
//
#include <hip/hip_runtime.h>

#define TT 512
#define HH 256

typedef _Float16 half2t __attribute__((ext_vector_type(2)));

// fp16-pair dot with fp32 accumulate (v_dot2_f32_f16 when available).
__device__ __forceinline__ float dot2acc(unsigned w, unsigned h, float acc) {
#if __has_builtin(__builtin_amdgcn_fdot2)
    return __builtin_amdgcn_fdot2(__builtin_bit_cast(half2t, w),
                                  __builtin_bit_cast(half2t, h), acc, false);
#else
    union U { unsigned u; _Float16 f[2]; };
    U uw, uh; uw.u = w; uh.u = h;
    acc = __builtin_fmaf((float)uw.f[0], (float)uh.f[0], acc);
    acc = __builtin_fmaf((float)uw.f[1], (float)uh.f[1], acc);
    return acc;
#endif
}

__device__ __forceinline__ unsigned packh2(float a, float b) {
    union U { _Float16 f[2]; unsigned u; } r;
    r.f[0] = (_Float16)a; r.f[1] = (_Float16)b;   // RNE conversion
    return r.u;
}

#define AGPR_W(dst, src) \
    asm volatile("v_accvgpr_write_b32 %0, %1" : "=a"(dst) : "v"(src))
#define AGPR_R(dst, src) \
    asm("v_accvgpr_read_b32 %0, %1" : "=v"(dst) : "a"(src))

// C=1, 1024 threads/wg, one wg per batch (128 wgs, plain launch).
// Thread j owns gate-row j: 128 packed fp16 words = 64 AGPR + 28 arch +
// 36 LDS. 16 waves = 4 waves/SIMD; per-wave budget 128 = 64 arch + 64 AGPR.
// h as 128 fp16-pair words in LDS (broadcast b128 reads). Row sum complete
// in-thread -> no reduction, 2 barriers/step, no exchange, no scratch.
//
// R19 change (single lever): the dot accumulation is split into FOUR
// independent chains (acc0..acc3, one per uint4 component). R18's single
// serial chain of 128 dependent v_dot2 (~6cyc latency each) left the SIMD
// latency-bound at VALUBusy=31%; 4 chains cut per-chain depth to 32 and
// let ds_read/accvgpr_read overlap FMA latency.
__global__ __launch_bounds__(1024)
__attribute__((amdgpu_waves_per_eu(4, 4)))
void lstm_single(
    const float* __restrict__ x,      // [B,T]
    const float* __restrict__ W_ih,   // [1024]
    const float* __restrict__ W_hh,   // [1024,256]
    const float* __restrict__ b_ih,   // [1024]
    const float* __restrict__ b_hh,   // [1024]
    const float* __restrict__ W1,     // [128,256]
    const float* __restrict__ b1,     // [128]
    const float* __restrict__ W2,     // [128]
    const float* __restrict__ b2,     // [1]
    float* __restrict__ out)          // [B]
{
    const int b = blockIdx.x;
    const int j = threadIdx.x;        // 0..1023 = gate-row

    __shared__ unsigned wl[9][1024][4];   // 144 KB: LDS weight tail (words 92..127)
    __shared__ unsigned h_lds[128];       // 512 B: h as fp16 pairs
    __shared__ float    h32[HH];          // 1 KB: h fp32 (epilogue)
    __shared__ float    gates[1024];      // 4 KB
    __shared__ float    x_lds[TT];        // 2 KB
    __shared__ float    red[128];         // 512 B
    // total ~152 KB -> 1 wg/CU

    const float* pR = W_hh + (size_t)j * HH;   // my row

    // ---- stage weights: words 0..63 -> 64 AGPRs
    unsigned wag[64];
    #pragma unroll
    for (int k = 0; k < 64; ++k) {
        unsigned p = packh2(pR[2 * k], pR[2 * k + 1]);
        AGPR_W(wag[k], p);
    }
    // ---- words 64..91 -> 28 arch VGPRs (opaque: no remat-from-global)
    unsigned wv[28];
    #pragma unroll
    for (int k = 0; k < 28; ++k)
        wv[k] = packh2(pR[2 * (64 + k)], pR[2 * (64 + k) + 1]);
    #pragma unroll
    for (int k = 0; k < 28; ++k)
        asm volatile("" : "+v"(wv[k]));
    // ---- words 92..127 -> LDS (9 uint4 blocks)
    #pragma unroll
    for (int blk = 0; blk < 9; ++blk) {
        #pragma unroll
        for (int u = 0; u < 4; ++u) {
            const int k = 2 * (92 + blk * 4 + u);
            wl[blk][j][u] = packh2(pR[k], pR[k + 1]);
        }
    }

    // per-row input weight + bias
    const float wih_r  = W_ih[j];
    const float bias_r = b_ih[j] + b_hh[j];

    // stage x; init h
    if (j < TT) x_lds[j] = x[(size_t)b * TT + j];
    if (j < 128) h_lds[j] = 0u;
    if (j < 256) h32[j] = 0.0f;
    float c = 0.0f;                   // cell state (threads 0..255, elem j)
    __syncthreads();

    for (int t = 0; t < TT; ++t) {
        const float xv = x_lds[t];    // independent LDS read, hoisted
        float acc0 = 0.f, acc1 = 0.f, acc2 = 0.f, acc3 = 0.f;
        const uint4* hq4 = reinterpret_cast<const uint4*>(h_lds);
        // ---- words 0..63: AGPR weights (16 uint4 h blocks), 4 chains
        #pragma unroll
        for (int i = 0; i < 16; ++i) {
            uint4 hq = hq4[i];                        // broadcast ds_read_b128
            unsigned w0, w1, w2, w3;
            AGPR_R(w0, wag[4*i+0]);
            AGPR_R(w1, wag[4*i+1]);
            AGPR_R(w2, wag[4*i+2]);
            AGPR_R(w3, wag[4*i+3]);
            acc0 = dot2acc(w0, hq.x, acc0);
            acc1 = dot2acc(w1, hq.y, acc1);
            acc2 = dot2acc(w2, hq.z, acc2);
            acc3 = dot2acc(w3, hq.w, acc3);
        }
        // ---- words 64..91: arch weights (7 uint4 h blocks), 4 chains
        #pragma unroll
        for (int i = 0; i < 7; ++i) {
            uint4 hq = hq4[16 + i];
            acc0 = dot2acc(wv[4*i+0], hq.x, acc0);
            acc1 = dot2acc(wv[4*i+1], hq.y, acc1);
            acc2 = dot2acc(wv[4*i+2], hq.z, acc2);
            acc3 = dot2acc(wv[4*i+3], hq.w, acc3);
        }
        // ---- words 92..127: LDS weights (9 uint4 blocks), 4 chains
        #pragma unroll
        for (int blk = 0; blk < 9; ++blk) {
            uint4 hq = hq4[23 + blk];
            uint4 wq = *reinterpret_cast<const uint4*>(&wl[blk][j][0]);
            acc0 = dot2acc(wq.x, hq.x, acc0);
            acc1 = dot2acc(wq.y, hq.y, acc1);
            acc2 = dot2acc(wq.z, hq.z, acc2);
            acc3 = dot2acc(wq.w, hq.w, acc3);
        }
        gates[j] = ((acc0 + acc1) + (acc2 + acc3))
                 + __builtin_fmaf(xv, wih_r, bias_r);
        __syncthreads();

        // ---- cell update: threads 0..255 (element j)
        if (j < 256) {
            float gi = gates[j];
            float gf = gates[256 + j];
            float gg = gates[512 + j];
            float go = gates[768 + j];
            gi = __builtin_amdgcn_rcpf(1.f + __expf(-gi));
            gf = __builtin_amdgcn_rcpf(1.f + __expf(-gf));
            go = __builtin_amdgcn_rcpf(1.f + __expf(-go));
            gg = 2.f * __builtin_amdgcn_rcpf(1.f + __expf(-2.f * gg)) - 1.f;
            c = __builtin_fmaf(gf, c, gi * gg);
            float th = 2.f * __builtin_amdgcn_rcpf(1.f + __expf(-2.f * c)) - 1.f;
            float hn = go * th;
            h32[j] = hn;
            reinterpret_cast<unsigned short*>(h_lds)[j] =
                __builtin_bit_cast(unsigned short, (_Float16)hn);
        }
        __syncthreads();
    }

    // ---- epilogue MLP: y = relu(h @ W1.T + b1) @ W2.T + b2
    if (j < 128) {
        const float4* w1p = reinterpret_cast<const float4*>(W1 + (size_t)j * HH);
        const float4* hp  = reinterpret_cast<const float4*>(h32);
        float s0 = 0.f, s1 = 0.f, s2 = 0.f, s3 = 0.f;
        #pragma unroll
        for (int k = 0; k < 64; ++k) {
            float4 wv4 = w1p[k], hv = hp[k];
            s0 = __builtin_fmaf(wv4.x, hv.x, s0);
            s1 = __builtin_fmaf(wv4.y, hv.y, s1);
            s2 = __builtin_fmaf(wv4.z, hv.z, s2);
            s3 = __builtin_fmaf(wv4.w, hv.w, s3);
        }
        float rv = fmaxf((s0 + s1) + (s2 + s3) + b1[j], 0.f);
        red[j] = rv * W2[j];
    }
    __syncthreads();
    if (j == 0) {
        float y = b2[0];
        #pragma unroll 4
        for (int k = 0; k < 128; ++k) y += red[k];
        out[b] = y;
    }
}

extern "C" void kernel_launch(void* const* d_in, const int* in_sizes, int n_in,
                              void* d_out, int out_size, void* d_ws, size_t ws_size,
                              hipStream_t stream) {
    const float* x    = (const float*)d_in[0];
    const float* W_ih = (const float*)d_in[1];
    const float* W_hh = (const float*)d_in[2];
    const float* b_ih = (const float*)d_in[3];
    const float* b_hh = (const float*)d_in[4];
    const float* W1   = (const float*)d_in[5];
    const float* b1   = (const float*)d_in[6];
    const float* W2   = (const float*)d_in[7];
    const float* b2   = (const float*)d_in[8];
    float* out = (float*)d_out;

    lstm_single<<<128, 1024, 0, stream>>>(x, W_ih, W_hh, b_ih, b_hh,
                                          W1, b1, W2, b2, out);
}